// Round 4
// baseline (624.776 us; speedup 1.0000x reference)
//
#include <hip/hip_runtime.h>
#include <stdint.h>

// ---------------------------------------------------------------------------
// GroupAttentionLayer: RF=16,STRIDE=16 windows tile the image exactly =>
//   yout = leaky(Q K^T / 16) V  (full dense attention per batch), then BN +
//   spatial softmax. BN mu/beta cancel in softmax; only g1*rsqrt(var+eps)
//   survives. B=4, P=4096 px/batch (T=16384 rows), C=256.
// Inputs fp32; OUTPUT fp32 (reference dtype — round-3 failure was writing
// bf16 into a float* buffer: bit-identical absmax across different impls).
// ---------------------------------------------------------------------------

typedef __attribute__((ext_vector_type(8))) short short8;   // 8 x bf16
typedef __attribute__((ext_vector_type(4))) float f32x4;    // MFMA 16x16 acc
typedef __attribute__((ext_vector_type(4))) unsigned short ushort4v;

#define ALPHA 0.3f
#define EPS   1e-3
#define NTOT  16384.0

__device__ __forceinline__ unsigned short f2bf(float f){
  unsigned u = __float_as_uint(f);
  u += 0x7FFFu + ((u>>16)&1u);          // RNE
  return (unsigned short)(u>>16);
}
__device__ __forceinline__ float lrelu(float x){ return x > 0.f ? x : ALPHA*x; }

// --------------------------------------------------------------- X fp32->bf16
__global__ __launch_bounds__(256)
void k_cvt(const float* __restrict__ X, unsigned short* __restrict__ Xb){
  int i = (blockIdx.x*256 + threadIdx.x)*4;
  float4 v = *(const float4*)(X + i);
  ushort4v o; o.x = f2bf(v.x); o.y = f2bf(v.y); o.z = f2bf(v.z); o.w = f2bf(v.w);
  *(ushort4v*)(Xb + i) = o;
}

// --------------------------------------------------------------- W transpose
// Wt[p*256 + d][c] = bf16(W_p[c][d])  (B^T operand layout for MFMA)
__global__ __launch_bounds__(256)
void k_wtrans(const float* __restrict__ Wq,
              const float* __restrict__ Wk,
              const float* __restrict__ Wv,
              unsigned short* __restrict__ Wt){
  int o = blockIdx.x*256 + threadIdx.x;          // 0 .. 196608
  int p = o >> 16, rem = o & 65535;
  int j = rem >> 8, c = rem & 255;
  const float* W = (p==0) ? Wq : ((p==1) ? Wk : Wv);
  Wt[o] = f2bf(W[c*256 + j]);
}

// --------------------------------------------------------------- QKV GEMM
// Y[t][n] = sum_c Xb[t][c] * Wt[n][c],  t<16384, n<768. fp32 out.
__global__ __launch_bounds__(256)
void k_qkv_gemm(const unsigned short* __restrict__ X,
                const unsigned short* __restrict__ Wt,
                float* __restrict__ Y){
  __shared__ __align__(16) unsigned short At[64*264];
  __shared__ __align__(16) unsigned short Bt[64*264];
  int tid = threadIdx.x;
  int mb = blockIdx.x, nb = blockIdx.y;
#pragma unroll
  for (int it = 0; it < 8; ++it){
    int s = it*256 + tid;
    int row = s >> 5, ch = s & 31;
    uint4 a = *(const uint4*)(X  + ((size_t)(mb*64 + row))*256 + ch*8);
    uint4 b = *(const uint4*)(Wt + ((size_t)(nb*64 + row))*256 + ch*8);
    *(uint4*)(At + row*264 + ch*8) = a;
    *(uint4*)(Bt + row*264 + ch*8) = b;
  }
  __syncthreads();
  int lane = tid & 63, wv = tid >> 6;
  int ln15 = lane & 15, quad = lane >> 4;
  int rw = (wv & 1)*32, cw = (wv >> 1)*32;     // 2x2 waves, 32x32 each
  f32x4 acc[2][2] = {};
#pragma unroll
  for (int ks = 0; ks < 8; ++ks){
    short8 afr[2], bfr[2];
#pragma unroll
    for (int mt = 0; mt < 2; ++mt){
      int r = rw + mt*16 + ln15;
      afr[mt] = *(const short8*)(At + r*264 + (ks*4+quad)*8);
    }
#pragma unroll
    for (int nt = 0; nt < 2; ++nt){
      int r = cw + nt*16 + ln15;
      bfr[nt] = *(const short8*)(Bt + r*264 + (ks*4+quad)*8);
    }
#pragma unroll
    for (int mt = 0; mt < 2; ++mt)
#pragma unroll
      for (int nt = 0; nt < 2; ++nt)
        acc[mt][nt] = __builtin_amdgcn_mfma_f32_16x16x32_bf16(afr[mt], bfr[nt], acc[mt][nt], 0,0,0);
  }
#pragma unroll
  for (int mt = 0; mt < 2; ++mt)
#pragma unroll
    for (int nt = 0; nt < 2; ++nt)
#pragma unroll
      for (int r = 0; r < 4; ++r){
        int row = mb*64 + rw + mt*16 + quad*4 + r;   // C/D: row = quad*4+reg
        int col = nb*64 + cw + nt*16 + ln15;         //      col = lane&15
        Y[(size_t)row*768 + col] = acc[mt][nt][r];
      }
}

// --------------------------------------------------------------- BN stats (Y)
__global__ __launch_bounds__(256)
void k_stats1(const float* __restrict__ Y, double* __restrict__ st){
  int tid = threadIdx.x;
  int r0 = blockIdx.x * 32;
  float sum[3] = {0,0,0}, sq[3] = {0,0,0};
#pragma unroll 4
  for (int r = 0; r < 32; ++r){
    const float* row = Y + (size_t)(r0 + r)*768;
#pragma unroll
    for (int cg = 0; cg < 3; ++cg){
      float v = row[cg*256 + tid];
      sum[cg] += v; sq[cg] += v*v;
    }
  }
#pragma unroll
  for (int cg = 0; cg < 3; ++cg){
    atomicAdd(&st[cg*256 + tid], (double)sum[cg]);
    atomicAdd(&st[768 + cg*256 + tid], (double)sq[cg]);
  }
}

// --------------------------------------------------------------- BN+leaky Q,K
__global__ __launch_bounds__(256)
void k_bn_qk(const float* __restrict__ Y, const double* __restrict__ st,
             const float* __restrict__ gq, const float* __restrict__ bq,
             const float* __restrict__ gk, const float* __restrict__ bk,
             unsigned short* __restrict__ Qb, unsigned short* __restrict__ Kb){
  int o = blockIdx.x*256 + threadIdx.x;
  int cc = o & 511;
  int t0 = (o >> 9) * 4;
  int proj = cc >> 8, c = cc & 255;
  double mu  = st[cc]     * (1.0/NTOT);
  double var = st[768+cc] * (1.0/NTOT) - mu*mu;
  float sc = (float)((proj ? gk[c] : gq[c]) / sqrt(var + EPS));
  float sh = (float)((proj ? bk[c] : bq[c]) - mu*sc);
  unsigned short* dst = proj ? Kb : Qb;
#pragma unroll
  for (int i = 0; i < 4; ++i){
    float v = Y[(size_t)(t0+i)*768 + cc];
    dst[(size_t)(t0+i)*256 + c] = f2bf(lrelu(v*sc + sh));
  }
}

// --------------------------------------------------------------- BN+leaky V^T
// Vt[b][c][p] (bf16) via LDS tile transpose
__global__ __launch_bounds__(256)
void k_bn_v(const float* __restrict__ Y, const double* __restrict__ st,
            const float* __restrict__ gv, const float* __restrict__ bv,
            unsigned short* __restrict__ Vt){
  __shared__ unsigned short tile[64][66];      // +2 pad: conflict-free col read
  int tid = threadIdx.x;
  int pt = blockIdx.x, ct = blockIdx.y, b = blockIdx.z;
  int cl = tid & 63, rq = tid >> 6;
  int c  = ct*64 + cl;          // v-channel for load phase
  int cc = 512 + c;
  double mu  = st[cc]     * (1.0/NTOT);
  double var = st[768+cc] * (1.0/NTOT) - mu*mu;
  float sc = (float)(gv[c] / sqrt(var + EPS));
  float sh = (float)(bv[c] - mu*sc);
#pragma unroll 4
  for (int k = 0; k < 16; ++k){
    int r = k*4 + rq;                                   // pixel-local
    size_t t = (size_t)b*4096 + pt*64 + r;
    float v = Y[t*768 + cc];
    tile[r][cl] = f2bf(lrelu(v*sc + sh));
  }
  __syncthreads();
#pragma unroll 4
  for (int k = 0; k < 16; ++k){
    int c2 = k*4 + rq;                                  // channel-local
    Vt[((size_t)b*256 + ct*64 + c2)*4096 + pt*64 + cl] = tile[cl][c2];
  }
}

// --------------------------------------------------------------- attention
// yout[b,q,c] = sum_keys leaky(Q.K/16) * V.  256 blocks (L&3=batch), 4 waves.
// BM=64 q-rows, BK=32 keys/iter, 128 iters. Plain staging, padded LDS rows.
__global__ __launch_bounds__(256)
void k_attn(const unsigned short* __restrict__ Qb,
            const unsigned short* __restrict__ Kb,
            const unsigned short* __restrict__ Vt,
            float* __restrict__ yout){
  __shared__ __align__(16) unsigned short Kl[32*264];  // [key][ch], 528B rows
  __shared__ __align__(16) unsigned short Vl[256*40];  // [ch][key], 80B rows
  __shared__ __align__(16) unsigned short Sl[64*40];   // [q][key],  80B rows
  int tid = threadIdx.x;
  int L = blockIdx.x;
  int b = L & 3, qt = L >> 2;
  int q0 = qt*64;
  int lane = tid & 63, wv = tid >> 6;
  int ln15 = lane & 15, quad = lane >> 4;

  // Q A-fragments: wave wv owns S-rows [wv*16, wv*16+16). A[m=lane&15][k]
  short8 qf[8];
  {
    const unsigned short* qrow = Qb + ((size_t)(b*4096 + q0 + wv*16 + ln15))*256 + quad*8;
#pragma unroll
    for (int ks = 0; ks < 8; ++ks) qf[ks] = *(const short8*)(qrow + ks*32);
  }

  f32x4 acc2[4][4] = {};   // wave wv: rows 0..64 x channels [wv*64, wv*64+64)

  for (int kt = 0; kt < 128; ++kt){
    // stage K (32x256) and V^T (256x32) tiles: global -> VGPR
    uint4 kr[4], vr[4];
#pragma unroll
    for (int it = 0; it < 4; ++it){
      int s = it*256 + tid;
      kr[it] = *(const uint4*)(Kb + ((size_t)(b*4096 + kt*32 + (s>>5)))*256 + (s&31)*8);
      vr[it] = *(const uint4*)(Vt + ((size_t)(b*256 + (s>>2)))*4096 + kt*32 + (s&3)*8);
    }
    __syncthreads();   // previous iteration's compute done; LDS reusable
#pragma unroll
    for (int it = 0; it < 4; ++it){
      int s = it*256 + tid;
      *(uint4*)(Kl + (s>>5)*264 + (s&31)*8) = kr[it];
      *(uint4*)(Vl + (s>>2)*40  + (s&3)*8)  = vr[it];
    }
    __syncthreads();   // tiles visible

    // phase 1: S[wv*16..+16][0..32) = Q . K^T
    f32x4 a1[2] = {};
#pragma unroll
    for (int ks = 0; ks < 8; ++ks){
#pragma unroll
      for (int nt = 0; nt < 2; ++nt){
        int r = nt*16 + ln15;
        short8 kf = *(const short8*)(Kl + r*264 + (ks*4+quad)*8);
        a1[nt] = __builtin_amdgcn_mfma_f32_16x16x32_bf16(qf[ks], kf, a1[nt], 0,0,0);
      }
    }
    // leaky(S/16) -> LDS bf16
#pragma unroll
    for (int nt = 0; nt < 2; ++nt)
#pragma unroll
      for (int r = 0; r < 4; ++r){
        int sr = wv*16 + quad*4 + r;       // C/D: row = quad*4+reg
        int scol = nt*16 + ln15;           //      col = lane&15
        Sl[sr*40 + scol] = f2bf(lrelu(a1[nt][r]*0.0625f));
      }
    __syncthreads();   // S visible

    // phase 2: acc2 += S[64][32] . V[32][256]
    short8 sf[4];
#pragma unroll
    for (int mt = 0; mt < 4; ++mt){
      int r = mt*16 + ln15;
      sf[mt] = *(const short8*)(Sl + r*40 + quad*8);
    }
#pragma unroll
    for (int nt = 0; nt < 4; ++nt){
      int cch = wv*64 + nt*16 + ln15;
      short8 vf = *(const short8*)(Vl + cch*40 + quad*8);
#pragma unroll
      for (int mt = 0; mt < 4; ++mt)
        acc2[mt][nt] = __builtin_amdgcn_mfma_f32_16x16x32_bf16(sf[mt], vf, acc2[mt][nt], 0,0,0);
    }
  }
#pragma unroll
  for (int mt = 0; mt < 4; ++mt)
#pragma unroll
    for (int nt = 0; nt < 4; ++nt)
#pragma unroll
      for (int r = 0; r < 4; ++r){
        int row = q0 + mt*16 + quad*4 + r;
        int col = wv*64 + nt*16 + ln15;
        yout[((size_t)b*4096 + row)*256 + col] = acc2[mt][nt][r];
      }
}

// --------------------------------------------------------------- yout stats
__global__ __launch_bounds__(256)
void k_stats2(const float* __restrict__ yout, double* __restrict__ st){
  int tid = threadIdx.x;
  int r0 = blockIdx.x*32;
  double sum = 0, sq = 0;
#pragma unroll 4
  for (int r = 0; r < 32; ++r){
    double v = (double)yout[(size_t)(r0+r)*256 + tid];
    sum += v; sq += v*v;
  }
  atomicAdd(&st[1536 + tid], sum);
  atomicAdd(&st[1792 + tid], sq);
}

// --------------------------------------------------------------- softmax
// out[b,p,c] = softmax_p( a_c * yout[b,p,c] ), a_c = g1_c*rsqrt(var_c+eps)
// OUTPUT IS FP32 (reference dtype).
__global__ __launch_bounds__(256)
void k_softmax(const float* __restrict__ yout, const double* __restrict__ st,
               const float* __restrict__ g1,
               float* __restrict__ out){
  __shared__ float red[256];
  int tid = threadIdx.x;
  int c0 = blockIdx.x*4, b = blockIdx.y;
  int c = c0 + (tid & 3), pr = tid >> 2;
  double mu  = st[1536 + c]*(1.0/NTOT);
  double var = st[1792 + c]*(1.0/NTOT) - mu*mu;
  float a = (float)(g1[c] / sqrt(var + EPS));
  const float* base = yout + (size_t)b*4096*256 + c;
  float m = -3.4e38f;
  for (int k = 0; k < 64; ++k)
    m = fmaxf(m, base[(size_t)(pr + k*64)*256] * a);
  red[tid] = m;
  __syncthreads();
  for (int off = 128; off >= 4; off >>= 1){
    if (tid < off) red[tid] = fmaxf(red[tid], red[tid+off]);
    __syncthreads();
  }
  m = red[tid & 3];
  __syncthreads();
  float l = 0.f;
  for (int k = 0; k < 64; ++k)
    l += __expf(base[(size_t)(pr + k*64)*256] * a - m);
  red[tid] = l;
  __syncthreads();
  for (int off = 128; off >= 4; off >>= 1){
    if (tid < off) red[tid] += red[tid+off];
    __syncthreads();
  }
  l = red[tid & 3];
  float rl = 1.f / l;
  for (int k = 0; k < 64; ++k){
    size_t idx = (size_t)(pr + k*64)*256;
    out[(size_t)b*4096*256 + c + idx] = __expf(base[idx]*a - m)*rl;
  }
}

// ---------------------------------------------------------------------------
extern "C" void kernel_launch(void* const* d_in, const int* in_sizes, int n_in,
                              void* d_out, int out_size, void* d_ws, size_t ws_size,
                              hipStream_t stream){
  (void)in_sizes; (void)n_in; (void)out_size; (void)ws_size;
  const float* X  = (const float*)d_in[0];
  const float* Wq = (const float*)d_in[1];
  const float* gq = (const float*)d_in[2];
  const float* bq = (const float*)d_in[3];
  const float* Wk = (const float*)d_in[4];
  const float* gk = (const float*)d_in[5];
  const float* bk = (const float*)d_in[6];
  const float* Wv = (const float*)d_in[7];
  const float* gv = (const float*)d_in[8];
  const float* bv = (const float*)d_in[9];
  const float* g1 = (const float*)d_in[10];
  // d_in[11] = b1: cancels inside the spatial softmax

  char* ws = (char*)d_ws;
  double*         st  = (double*)ws;                        // 2048 f64 (16KB)
  unsigned short* Wt  = (unsigned short*)(ws + 16384);      // 768x256 bf16
  unsigned short* Xb  = (unsigned short*)(ws + 409600);     // 16384x256 bf16
  float*          Y   = (float*)(ws + 8798208);             // 16384x768 f32
  unsigned short* Kb  = (unsigned short*)(ws + 59129856);   // 16384x256 bf16
  unsigned short* Vt  = (unsigned short*)(ws + 67518464);   // [4][256][4096] bf16
  // reuse: Qb overlays Xb (dead after GEMM); yout overlays Y (dead after bn_v)
  unsigned short* Qb  = Xb;
  float*          yo  = Y;

  hipMemsetAsync(st, 0, 16384, stream);
  k_cvt     <<<4096, 256, 0, stream>>>(X, Xb);
  k_wtrans  <<<768, 256, 0, stream>>>(Wq, Wk, Wv, Wt);
  k_qkv_gemm<<<dim3(256,12), 256, 0, stream>>>(Xb, Wt, Y);
  k_stats1  <<<512, 256, 0, stream>>>(Y, st);
  k_bn_qk   <<<8192, 256, 0, stream>>>(Y, st, gq, bq, gk, bk, Qb, Kb);
  k_bn_v    <<<dim3(64,4,4), 256, 0, stream>>>(Y, st, gv, bv, Vt);
  k_attn    <<<256, 256, 0, stream>>>(Qb, Kb, Vt, yo);
  k_stats2  <<<512, 256, 0, stream>>>(yo, st);
  k_softmax <<<dim3(64,4), 256, 0, stream>>>(yo, st, g1, (float*)d_out);
}

// Round 5
// 383.059 us; speedup vs baseline: 1.6310x; 1.6310x over previous
//
#include <hip/hip_runtime.h>
#include <stdint.h>

// ---------------------------------------------------------------------------
// GroupAttentionLayer: RF=16,STRIDE=16 windows tile the image exactly =>
//   yout = leaky(Q K^T / 16) V  (full dense attention per batch), then BN +
//   spatial softmax (mu/beta cancel; only a_c = g1/sqrt(var+eps) survives;
//   BN unit-variance makes the max-pass unnecessary: args are z-scores).
// B=4, P=4096 px/batch (T=16384 rows), C=256. Inputs fp32, OUTPUT fp32.
// R5: k_attn rewritten: 512 blocks (64 qt x 4 b x 2 key-halves; blk&7 pins
// (b,half) to one XCD whose L2 holds its 2MB K/V), 8 waves, BK=128,
// 32x32x16 MFMA, K/V frags straight from L2, only S through LDS.
// ---------------------------------------------------------------------------

typedef __attribute__((ext_vector_type(8)))  short short8;   // 8 x bf16
typedef __attribute__((ext_vector_type(4)))  float f32x4;    // 16x16 acc
typedef __attribute__((ext_vector_type(16))) float f32x16;   // 32x32 acc
typedef __attribute__((ext_vector_type(4)))  unsigned short ushort4v;

#define ALPHA 0.3f
#define EPS   1e-3
#define NTOT  16384.0

__device__ __forceinline__ unsigned short f2bf(float f){
  unsigned u = __float_as_uint(f);
  u += 0x7FFFu + ((u>>16)&1u);          // RNE
  return (unsigned short)(u>>16);
}
__device__ __forceinline__ float lrelu(float x){ return x > 0.f ? x : ALPHA*x; }

// --------------------------------------------------------------- X fp32->bf16
__global__ __launch_bounds__(256)
void k_cvt(const float* __restrict__ X, unsigned short* __restrict__ Xb){
  int i = (blockIdx.x*256 + threadIdx.x)*4;
  float4 v = *(const float4*)(X + i);
  ushort4v o; o.x = f2bf(v.x); o.y = f2bf(v.y); o.z = f2bf(v.z); o.w = f2bf(v.w);
  *(ushort4v*)(Xb + i) = o;
}

// --------------------------------------------------------------- W transpose
__global__ __launch_bounds__(256)
void k_wtrans(const float* __restrict__ Wq,
              const float* __restrict__ Wk,
              const float* __restrict__ Wv,
              unsigned short* __restrict__ Wt){
  int o = blockIdx.x*256 + threadIdx.x;          // 0 .. 196608
  int p = o >> 16, rem = o & 65535;
  int j = rem >> 8, c = rem & 255;
  const float* W = (p==0) ? Wq : ((p==1) ? Wk : Wv);
  Wt[o] = f2bf(W[c*256 + j]);
}

// --------------------------------------------------------------- QKV GEMM
// Y[t][n] = sum_c Xb[t][c] * Wt[n][c],  t<16384, n<768. fp32 out.
__global__ __launch_bounds__(256)
void k_qkv_gemm(const unsigned short* __restrict__ X,
                const unsigned short* __restrict__ Wt,
                float* __restrict__ Y){
  __shared__ __align__(16) unsigned short At[64*264];
  __shared__ __align__(16) unsigned short Bt[64*264];
  int tid = threadIdx.x;
  int mb = blockIdx.x, nb = blockIdx.y;
#pragma unroll
  for (int it = 0; it < 8; ++it){
    int s = it*256 + tid;
    int row = s >> 5, ch = s & 31;
    uint4 a = *(const uint4*)(X  + ((size_t)(mb*64 + row))*256 + ch*8);
    uint4 b = *(const uint4*)(Wt + ((size_t)(nb*64 + row))*256 + ch*8);
    *(uint4*)(At + row*264 + ch*8) = a;
    *(uint4*)(Bt + row*264 + ch*8) = b;
  }
  __syncthreads();
  int lane = tid & 63, wv = tid >> 6;
  int ln15 = lane & 15, quad = lane >> 4;
  int rw = (wv & 1)*32, cw = (wv >> 1)*32;     // 2x2 waves, 32x32 each
  f32x4 acc[2][2] = {};
#pragma unroll
  for (int ks = 0; ks < 8; ++ks){
    short8 afr[2], bfr[2];
#pragma unroll
    for (int mt = 0; mt < 2; ++mt){
      int r = rw + mt*16 + ln15;
      afr[mt] = *(const short8*)(At + r*264 + (ks*4+quad)*8);
    }
#pragma unroll
    for (int nt = 0; nt < 2; ++nt){
      int r = cw + nt*16 + ln15;
      bfr[nt] = *(const short8*)(Bt + r*264 + (ks*4+quad)*8);
    }
#pragma unroll
    for (int mt = 0; mt < 2; ++mt)
#pragma unroll
      for (int nt = 0; nt < 2; ++nt)
        acc[mt][nt] = __builtin_amdgcn_mfma_f32_16x16x32_bf16(afr[mt], bfr[nt], acc[mt][nt], 0,0,0);
  }
#pragma unroll
  for (int mt = 0; mt < 2; ++mt)
#pragma unroll
    for (int nt = 0; nt < 2; ++nt)
#pragma unroll
      for (int r = 0; r < 4; ++r){
        int row = mb*64 + rw + mt*16 + quad*4 + r;   // C/D: row = quad*4+reg
        int col = nb*64 + cw + nt*16 + ln15;         //      col = lane&15
        Y[(size_t)row*768 + col] = acc[mt][nt][r];
      }
}

// --------------------------------------------------------------- BN stats (Y)
__global__ __launch_bounds__(256)
void k_stats1(const float* __restrict__ Y, double* __restrict__ st){
  int tid = threadIdx.x;
  int r0 = blockIdx.x * 32;
  float sum[3] = {0,0,0}, sq[3] = {0,0,0};
#pragma unroll 4
  for (int r = 0; r < 32; ++r){
    const float* row = Y + (size_t)(r0 + r)*768;
#pragma unroll
    for (int cg = 0; cg < 3; ++cg){
      float v = row[cg*256 + tid];
      sum[cg] += v; sq[cg] += v*v;
    }
  }
#pragma unroll
  for (int cg = 0; cg < 3; ++cg){
    atomicAdd(&st[cg*256 + tid], (double)sum[cg]);
    atomicAdd(&st[768 + cg*256 + tid], (double)sq[cg]);
  }
}

// --------------------------------------------------------------- BN+leaky Q,K
__global__ __launch_bounds__(256)
void k_bn_qk(const float* __restrict__ Y, const double* __restrict__ st,
             const float* __restrict__ gq, const float* __restrict__ bq,
             const float* __restrict__ gk, const float* __restrict__ bk,
             unsigned short* __restrict__ Qb, unsigned short* __restrict__ Kb){
  int o = blockIdx.x*256 + threadIdx.x;
  int cc = o & 511;
  int t0 = (o >> 9) * 4;
  int proj = cc >> 8, c = cc & 255;
  double mu  = st[cc]     * (1.0/NTOT);
  double var = st[768+cc] * (1.0/NTOT) - mu*mu;
  float sc = (float)((proj ? gk[c] : gq[c]) / sqrt(var + EPS));
  float sh = (float)((proj ? bk[c] : bq[c]) - mu*sc);
  unsigned short* dst = proj ? Kb : Qb;
#pragma unroll
  for (int i = 0; i < 4; ++i){
    float v = Y[(size_t)(t0+i)*768 + cc];
    dst[(size_t)(t0+i)*256 + c] = f2bf(lrelu(v*sc + sh));
  }
}

// --------------------------------------------------------------- BN+leaky V^T
__global__ __launch_bounds__(256)
void k_bn_v(const float* __restrict__ Y, const double* __restrict__ st,
            const float* __restrict__ gv, const float* __restrict__ bv,
            unsigned short* __restrict__ Vt){
  __shared__ unsigned short tile[64][66];
  int tid = threadIdx.x;
  int pt = blockIdx.x, ct = blockIdx.y, b = blockIdx.z;
  int cl = tid & 63, rq = tid >> 6;
  int c  = ct*64 + cl;
  int cc = 512 + c;
  double mu  = st[cc]     * (1.0/NTOT);
  double var = st[768+cc] * (1.0/NTOT) - mu*mu;
  float sc = (float)(gv[c] / sqrt(var + EPS));
  float sh = (float)(bv[c] - mu*sc);
#pragma unroll 4
  for (int k = 0; k < 16; ++k){
    int r = k*4 + rq;
    size_t t = (size_t)b*4096 + pt*64 + r;
    float v = Y[t*768 + cc];
    tile[r][cl] = f2bf(lrelu(v*sc + sh));
  }
  __syncthreads();
#pragma unroll 4
  for (int k = 0; k < 16; ++k){
    int c2 = k*4 + rq;
    Vt[((size_t)b*256 + ct*64 + c2)*4096 + pt*64 + cl] = tile[cl][c2];
  }
}

// --------------------------------------------------------------- attention
// 512 blocks x 512 threads. blk>>3 = q-tile (64 rows), blk&7 = (b,half):
// consecutive blk -> XCD round-robin => each XCD sees ONE (b,half) whose
// K/V (2MB) is L2-resident. 16 iters of BK=128 keys; 32x32x16 MFMA.
// Phase1: wave w=(mi=w&1, ni=w>>2..): tile rows mi*32, keys ni*32; K frags
// from L2. S (64x128 bf16) through LDS. Phase2: wave w owns 32 channels.
__global__ __launch_bounds__(512)
void k_attn(const unsigned short* __restrict__ Qb,
            const unsigned short* __restrict__ Kb,
            const unsigned short* __restrict__ Vt,
            float* __restrict__ P0, float* __restrict__ P1){
  __shared__ __align__(16) unsigned short Sl[64*136];   // [q][key], 136-pad
  int tid = threadIdx.x;
  int blk = blockIdx.x;
  int qt = blk >> 3, combo = blk & 7;
  int b = combo >> 1, half = combo & 1;
  int q0 = qt*64;
  int lane = tid & 63, w = tid >> 6;
  int l31 = lane & 31, l5 = lane >> 5;
  int mi = w & 1, ni = w >> 1;                 // phase-1 tile coords
  float* P = half ? P1 : P0;

  // Q A-frags (resident): rows q0+mi*32+l31, K=256 in 16 ksteps.
  // A[m=lane&31][k=(lane>>5)*8+j]
  short8 qf[16];
  {
    const unsigned short* qr = Qb + ((size_t)(b*4096 + q0 + mi*32 + l31))*256 + l5*8;
#pragma unroll
    for (int ks = 0; ks < 16; ++ks) qf[ks] = *(const short8*)(qr + ks*16);
  }
  f32x16 acc2[2] = {};    // phase-2: [mt] = 32q x 32ch tile

  const unsigned short* kbase = Kb + ((size_t)(b*4096 + half*2048 + ni*32 + l31))*256 + l5*8;
  const unsigned short* vbase = Vt + ((size_t)(b*256 + w*32 + l31))*4096 + half*2048 + l5*8;

  for (int kt = 0; kt < 16; ++kt){
    // phase 1: S-tile(mi,ni) = Q . K^T over K=256
    f32x16 a1 = {};
#pragma unroll
    for (int ks = 0; ks < 16; ++ks){
      short8 kf = *(const short8*)(kbase + (size_t)kt*128*256 + ks*16);
      a1 = __builtin_amdgcn_mfma_f32_32x32x16_bf16(qf[ks], kf, a1, 0, 0, 0);
    }
    // leaky(S/16) -> LDS bf16. C/D 32x32: row=(reg&3)+8*(reg>>2)+4*l5, col=l31
#pragma unroll
    for (int reg = 0; reg < 16; ++reg){
      int rt = (reg & 3) + 8*(reg >> 2) + 4*l5;
      Sl[(mi*32 + rt)*136 + ni*32 + l31] = f2bf(lrelu(a1[reg]*0.0625f));
    }
    __syncthreads();     // S visible
    // phase 2: acc2 += S[64x128] . V^T[ch][key], V frags from L2
#pragma unroll
    for (int kk = 0; kk < 8; ++kk){
      short8 vf = *(const short8*)(vbase + (size_t)kt*128 + kk*16);
#pragma unroll
      for (int mt = 0; mt < 2; ++mt){
        short8 sf = *(const short8*)(Sl + (mt*32 + l31)*136 + kk*16 + l5*8);
        acc2[mt] = __builtin_amdgcn_mfma_f32_32x32x16_bf16(sf, vf, acc2[mt], 0, 0, 0);
      }
    }
    __syncthreads();     // S consumed; next iter may overwrite
  }
#pragma unroll
  for (int mt = 0; mt < 2; ++mt)
#pragma unroll
    for (int reg = 0; reg < 16; ++reg){
      int row = q0 + mt*32 + (reg & 3) + 8*(reg >> 2) + 4*l5;
      P[((size_t)b*4096 + row)*256 + w*32 + l31] = acc2[mt][reg];
    }
}

// ------------------------------------------------- partial reduce + BN stats
__global__ __launch_bounds__(256)
void k_red(const float* __restrict__ P0, const float* __restrict__ P1,
           float* __restrict__ yout, double* __restrict__ st){
  int tid = threadIdx.x;
  int r0 = blockIdx.x*32;
  double sum = 0, sq = 0;
#pragma unroll 4
  for (int r = 0; r < 32; ++r){
    size_t idx = (size_t)(r0 + r)*256 + tid;
    float v = P0[idx] + P1[idx];
    yout[idx] = v;
    sum += v; sq += (double)v*v;
  }
  atomicAdd(&st[1536 + tid], sum);
  atomicAdd(&st[1792 + tid], sq);
}

// --------------------------------------------------------------- softmax
// BN => args are z-scores (|arg|<~6): no max pass needed; shift by a*mu.
// pass 1: sums[b][c] += sum_px exp(a*yout - a*mu)
__global__ __launch_bounds__(256)
void k_soft1(const float* __restrict__ yout, const double* __restrict__ st,
             const float* __restrict__ g1, float* __restrict__ sums){
  __shared__ float red[256];
  __shared__ float sA[64], sK[64];
  int tid = threadIdx.x;
  int chunk = blockIdx.x, ct = blockIdx.y, b = blockIdx.z;
  int cl = tid & 63, pg = tid >> 6;
  int c = ct*64 + cl;
  if (tid < 64){
    int cc = ct*64 + tid;
    double mu  = st[1536 + cc]*(1.0/NTOT);
    double var = st[1792 + cc]*(1.0/NTOT) - mu*mu;
    double a = g1[cc] / sqrt(var + EPS);
    sA[tid] = (float)a;
    sK[tid] = (float)(a*mu);
  }
  __syncthreads();
  float a = sA[cl], K = sK[cl];
  float s = 0.f;
  const float* base = yout + ((size_t)b*4096 + chunk*256)*256 + c;
#pragma unroll 4
  for (int k = 0; k < 64; ++k){
    float v = base[(size_t)(pg + k*4)*256];
    s += __expf(v*a - K);
  }
  red[tid] = s;
  __syncthreads();
  if (tid < 64){
    float tot = red[tid] + red[64+tid] + red[128+tid] + red[192+tid];
    atomicAdd(&sums[b*256 + ct*64 + tid], tot);
  }
}

// pass 2: out = exp(a*yout - a*mu) / sums
__global__ __launch_bounds__(256)
void k_soft2(const float* __restrict__ yout, const double* __restrict__ st,
             const float* __restrict__ g1, const float* __restrict__ sums,
             float* __restrict__ out){
  __shared__ float sA[64], sK[64], sR[64];
  int tid = threadIdx.x;
  int chunk = blockIdx.x, ct = blockIdx.y, b = blockIdx.z;
  int cl = tid & 63, pg = tid >> 6;
  int c = ct*64 + cl;
  if (tid < 64){
    int cc = ct*64 + tid;
    double mu  = st[1536 + cc]*(1.0/NTOT);
    double var = st[1792 + cc]*(1.0/NTOT) - mu*mu;
    double a = g1[cc] / sqrt(var + EPS);
    sA[tid] = (float)a;
    sK[tid] = (float)(a*mu);
    sR[tid] = 1.f / sums[b*256 + cc];
  }
  __syncthreads();
  float a = sA[cl], K = sK[cl], rl = sR[cl];
  const float* base = yout + ((size_t)b*4096 + chunk*256)*256 + c;
  float* obase = out + ((size_t)b*4096 + chunk*256)*256 + c;
#pragma unroll 4
  for (int k = 0; k < 64; ++k){
    size_t idx = (size_t)(pg + k*4)*256;
    obase[idx] = __expf(base[idx]*a - K) * rl;
  }
}

// ---------------------------------------------------------------------------
extern "C" void kernel_launch(void* const* d_in, const int* in_sizes, int n_in,
                              void* d_out, int out_size, void* d_ws, size_t ws_size,
                              hipStream_t stream){
  (void)in_sizes; (void)n_in; (void)out_size; (void)ws_size;
  const float* X  = (const float*)d_in[0];
  const float* Wq = (const float*)d_in[1];
  const float* gq = (const float*)d_in[2];
  const float* bq = (const float*)d_in[3];
  const float* Wk = (const float*)d_in[4];
  const float* gk = (const float*)d_in[5];
  const float* bk = (const float*)d_in[6];
  const float* Wv = (const float*)d_in[7];
  const float* gv = (const float*)d_in[8];
  const float* bv = (const float*)d_in[9];
  const float* g1 = (const float*)d_in[10];
  // d_in[11] = b1: cancels inside the spatial softmax

  char* ws = (char*)d_ws;
  double*         st   = (double*)ws;                        // 2048 f64 (16KB)
  float*          sums = (float*)(ws + 16384);               // 4x256 f32 (4KB)
  unsigned short* Wt   = (unsigned short*)(ws + 20480);      // 768x256 bf16
  unsigned short* Xb   = (unsigned short*)(ws + 413696);     // 16384x256 bf16
  float*          Y    = (float*)(ws + 8802304);             // 16384x768 f32 (48MB)
  unsigned short* Kb   = (unsigned short*)(ws + 59133952);   // 16384x256 bf16
  unsigned short* Vt   = (unsigned short*)(ws + 67522560);   // [4][256][4096] bf16
  // Y region is dead after k_bn_v; reuse it for P0|P1|yout (3x16MB = 48MB)
  unsigned short* Qb   = Xb;                                 // dead after GEMM
  float*          P0   = Y;
  float*          P1   = (float*)((char*)Y + 16777216);
  float*          yo   = (float*)((char*)Y + 33554432);

  hipMemsetAsync(st, 0, 20480, stream);
  k_cvt     <<<4096, 256, 0, stream>>>(X, Xb);
  k_wtrans  <<<768, 256, 0, stream>>>(Wq, Wk, Wv, Wt);
  k_qkv_gemm<<<dim3(256,12), 256, 0, stream>>>(Xb, Wt, Y);
  k_stats1  <<<512, 256, 0, stream>>>(Y, st);
  k_bn_qk   <<<8192, 256, 0, stream>>>(Y, st, gq, bq, gk, bk, Qb, Kb);
  k_bn_v    <<<dim3(64,4,4), 256, 0, stream>>>(Y, st, gv, bv, Vt);
  k_attn    <<<512, 512, 0, stream>>>(Qb, Kb, Vt, P0, P1);
  k_red     <<<512, 256, 0, stream>>>(P0, P1, yo, st);
  k_soft1   <<<dim3(16,4,4), 256, 0, stream>>>(yo, st, g1, sums);
  k_soft2   <<<dim3(16,4,4), 256, 0, stream>>>(yo, st, g1, sums, (float*)d_out);
}

// Round 6
// 351.423 us; speedup vs baseline: 1.7778x; 1.0900x over previous
//
#include <hip/hip_runtime.h>
#include <stdint.h>

// ---------------------------------------------------------------------------
// GroupAttentionLayer: RF=16,STRIDE=16 windows tile the image exactly =>
//   yout = leaky(Q K^T / 16) V  (full dense attention per batch), then BN +
//   spatial softmax (mu/beta cancel; only a_c = g1/sqrt(var+eps) survives;
//   BN unit-variance makes the max-pass unnecessary: args are z-scores).
// B=4, P=4096 px/batch (T=16384 rows), C=256. Inputs fp32, OUTPUT fp32.
// R6: k_attn: Q tile in LDS (VGPR<=128 -> 2 blocks/CU resident), BK=256
// (8 iters x 2 barriers), 2 independent MFMA chains per wave in phase 1,
// phase-1 compute overlaps other waves' phase-2 across the barrier.
// ---------------------------------------------------------------------------

typedef __attribute__((ext_vector_type(8)))  short short8;   // 8 x bf16
typedef __attribute__((ext_vector_type(4)))  float f32x4;    // 16x16 acc
typedef __attribute__((ext_vector_type(16))) float f32x16;   // 32x32 acc
typedef __attribute__((ext_vector_type(4)))  unsigned short ushort4v;

#define ALPHA 0.3f
#define EPS   1e-3
#define NTOT  16384.0

__device__ __forceinline__ unsigned short f2bf(float f){
  unsigned u = __float_as_uint(f);
  u += 0x7FFFu + ((u>>16)&1u);          // RNE
  return (unsigned short)(u>>16);
}
__device__ __forceinline__ float lrelu(float x){ return x > 0.f ? x : ALPHA*x; }

// --------------------------------------------------------------- X fp32->bf16
__global__ __launch_bounds__(256)
void k_cvt(const float* __restrict__ X, unsigned short* __restrict__ Xb){
  int i = (blockIdx.x*256 + threadIdx.x)*4;
  float4 v = *(const float4*)(X + i);
  ushort4v o; o.x = f2bf(v.x); o.y = f2bf(v.y); o.z = f2bf(v.z); o.w = f2bf(v.w);
  *(ushort4v*)(Xb + i) = o;
}

// --------------------------------------------------------------- W transpose
__global__ __launch_bounds__(256)
void k_wtrans(const float* __restrict__ Wq,
              const float* __restrict__ Wk,
              const float* __restrict__ Wv,
              unsigned short* __restrict__ Wt){
  int o = blockIdx.x*256 + threadIdx.x;          // 0 .. 196608
  int p = o >> 16, rem = o & 65535;
  int j = rem >> 8, c = rem & 255;
  const float* W = (p==0) ? Wq : ((p==1) ? Wk : Wv);
  Wt[o] = f2bf(W[c*256 + j]);
}

// --------------------------------------------------------------- QKV GEMM
// Y[t][n] = sum_c Xb[t][c] * Wt[n][c],  t<16384, n<768. fp32 out.
__global__ __launch_bounds__(256)
void k_qkv_gemm(const unsigned short* __restrict__ X,
                const unsigned short* __restrict__ Wt,
                float* __restrict__ Y){
  __shared__ __align__(16) unsigned short At[64*264];
  __shared__ __align__(16) unsigned short Bt[64*264];
  int tid = threadIdx.x;
  int mb = blockIdx.x, nb = blockIdx.y;
#pragma unroll
  for (int it = 0; it < 8; ++it){
    int s = it*256 + tid;
    int row = s >> 5, ch = s & 31;
    uint4 a = *(const uint4*)(X  + ((size_t)(mb*64 + row))*256 + ch*8);
    uint4 b = *(const uint4*)(Wt + ((size_t)(nb*64 + row))*256 + ch*8);
    *(uint4*)(At + row*264 + ch*8) = a;
    *(uint4*)(Bt + row*264 + ch*8) = b;
  }
  __syncthreads();
  int lane = tid & 63, wv = tid >> 6;
  int ln15 = lane & 15, quad = lane >> 4;
  int rw = (wv & 1)*32, cw = (wv >> 1)*32;     // 2x2 waves, 32x32 each
  f32x4 acc[2][2] = {};
#pragma unroll
  for (int ks = 0; ks < 8; ++ks){
    short8 afr[2], bfr[2];
#pragma unroll
    for (int mt = 0; mt < 2; ++mt){
      int r = rw + mt*16 + ln15;
      afr[mt] = *(const short8*)(At + r*264 + (ks*4+quad)*8);
    }
#pragma unroll
    for (int nt = 0; nt < 2; ++nt){
      int r = cw + nt*16 + ln15;
      bfr[nt] = *(const short8*)(Bt + r*264 + (ks*4+quad)*8);
    }
#pragma unroll
    for (int mt = 0; mt < 2; ++mt)
#pragma unroll
      for (int nt = 0; nt < 2; ++nt)
        acc[mt][nt] = __builtin_amdgcn_mfma_f32_16x16x32_bf16(afr[mt], bfr[nt], acc[mt][nt], 0,0,0);
  }
#pragma unroll
  for (int mt = 0; mt < 2; ++mt)
#pragma unroll
    for (int nt = 0; nt < 2; ++nt)
#pragma unroll
      for (int r = 0; r < 4; ++r){
        int row = mb*64 + rw + mt*16 + quad*4 + r;   // C/D: row = quad*4+reg
        int col = nb*64 + cw + nt*16 + ln15;         //      col = lane&15
        Y[(size_t)row*768 + col] = acc[mt][nt][r];
      }
}

// --------------------------------------------------------------- BN stats (Y)
__global__ __launch_bounds__(256)
void k_stats1(const float* __restrict__ Y, double* __restrict__ st){
  int tid = threadIdx.x;
  int r0 = blockIdx.x * 32;
  float sum[3] = {0,0,0}, sq[3] = {0,0,0};
#pragma unroll 4
  for (int r = 0; r < 32; ++r){
    const float* row = Y + (size_t)(r0 + r)*768;
#pragma unroll
    for (int cg = 0; cg < 3; ++cg){
      float v = row[cg*256 + tid];
      sum[cg] += v; sq[cg] += v*v;
    }
  }
#pragma unroll
  for (int cg = 0; cg < 3; ++cg){
    atomicAdd(&st[cg*256 + tid], (double)sum[cg]);
    atomicAdd(&st[768 + cg*256 + tid], (double)sq[cg]);
  }
}

// --------------------------------------------------------------- BN+leaky Q,K
__global__ __launch_bounds__(256)
void k_bn_qk(const float* __restrict__ Y, const double* __restrict__ st,
             const float* __restrict__ gq, const float* __restrict__ bq,
             const float* __restrict__ gk, const float* __restrict__ bk,
             unsigned short* __restrict__ Qb, unsigned short* __restrict__ Kb){
  int o = blockIdx.x*256 + threadIdx.x;
  int cc = o & 511;
  int t0 = (o >> 9) * 4;
  int proj = cc >> 8, c = cc & 255;
  double mu  = st[cc]     * (1.0/NTOT);
  double var = st[768+cc] * (1.0/NTOT) - mu*mu;
  float sc = (float)((proj ? gk[c] : gq[c]) / sqrt(var + EPS));
  float sh = (float)((proj ? bk[c] : bq[c]) - mu*sc);
  unsigned short* dst = proj ? Kb : Qb;
#pragma unroll
  for (int i = 0; i < 4; ++i){
    float v = Y[(size_t)(t0+i)*768 + cc];
    dst[(size_t)(t0+i)*256 + c] = f2bf(lrelu(v*sc + sh));
  }
}

// --------------------------------------------------------------- BN+leaky V^T
__global__ __launch_bounds__(256)
void k_bn_v(const float* __restrict__ Y, const double* __restrict__ st,
            const float* __restrict__ gv, const float* __restrict__ bv,
            unsigned short* __restrict__ Vt){
  __shared__ unsigned short tile[64][66];
  int tid = threadIdx.x;
  int pt = blockIdx.x, ct = blockIdx.y, b = blockIdx.z;
  int cl = tid & 63, rq = tid >> 6;
  int c  = ct*64 + cl;
  int cc = 512 + c;
  double mu  = st[cc]     * (1.0/NTOT);
  double var = st[768+cc] * (1.0/NTOT) - mu*mu;
  float sc = (float)(gv[c] / sqrt(var + EPS));
  float sh = (float)(bv[c] - mu*sc);
#pragma unroll 4
  for (int k = 0; k < 16; ++k){
    int r = k*4 + rq;
    size_t t = (size_t)b*4096 + pt*64 + r;
    float v = Y[t*768 + cc];
    tile[r][cl] = f2bf(lrelu(v*sc + sh));
  }
  __syncthreads();
#pragma unroll 4
  for (int k = 0; k < 16; ++k){
    int c2 = k*4 + rq;
    Vt[((size_t)b*256 + ct*64 + c2)*4096 + pt*64 + cl] = tile[cl][c2];
  }
}

// --------------------------------------------------------------- attention
// 512 blocks x 512 threads. blk>>3 = q-tile (64 rows), blk&7 = (b,half):
// consecutive blk -> XCD round-robin => each XCD sees ONE (b,half) whose
// K/V (2MB) is L2-resident. 8 iters of BK=256; 32x32x16 MFMA.
// Q tile in LDS (keeps VGPR<=128 -> 2 blocks/CU). Phase1: wave (mi=w&1,
// nj=w>>1): rows mi*32, keys nj*64 as TWO independent 32-key chains.
// Phase2: wave w owns 32 channels, full 256 keys. 2 barriers/iter; phase-1
// compute sits before the first barrier to overlap others' phase-2.
__global__ __launch_bounds__(512, 4)
void k_attn(const unsigned short* __restrict__ Qb,
            const unsigned short* __restrict__ Kb,
            const unsigned short* __restrict__ Vt,
            float* __restrict__ P0, float* __restrict__ P1){
  __shared__ __align__(16) unsigned short Ql[64*264];   // [q][ch], 528B rows
  __shared__ __align__(16) unsigned short Sl[64*264];   // [q][key], 528B rows
  int tid = threadIdx.x;
  int blk = blockIdx.x;
  int qt = blk >> 3, combo = blk & 7;
  int b = combo >> 1, half = combo & 1;
  int q0 = qt*64;
  int lane = tid & 63, w = tid >> 6;
  int l31 = lane & 31, l5 = lane >> 5;
  int mi = w & 1, nj = w >> 1;                 // phase-1 tile coords
  float* P = half ? P1 : P0;

  // stage Q tile 64x256 bf16 (once)
#pragma unroll
  for (int it = 0; it < 4; ++it){
    int s = it*512 + tid;
    int row = s >> 5, ch = s & 31;
    *(uint4*)(Ql + row*264 + ch*8) =
        *(const uint4*)(Qb + ((size_t)(b*4096 + q0 + row))*256 + ch*8);
  }

  f32x16 acc2[2] = {};    // phase-2: [mt] = 32q x 32ch
  const unsigned short* kbase = Kb + ((size_t)(b*4096 + half*2048 + nj*64 + l31))*256 + l5*8;
  const unsigned short* vbase = Vt + ((size_t)(b*256 + w*32 + l31))*4096 + half*2048 + l5*8;
  const unsigned short* qa    = Ql + (mi*32 + l31)*264 + l5*8;

  __syncthreads();       // Q visible

  for (int kt = 0; kt < 8; ++kt){
    // phase 1: two independent chains (keys nj*64+{0..31}, {32..63})
    f32x16 a1[2] = {};
#pragma unroll
    for (int ks = 0; ks < 16; ++ks){
      short8 qv = *(const short8*)(qa + ks*16);
      short8 k0 = *(const short8*)(kbase + ((size_t)kt*256      )*256 + ks*16);
      short8 k1 = *(const short8*)(kbase + ((size_t)kt*256 + 32 )*256 + ks*16);
      a1[0] = __builtin_amdgcn_mfma_f32_32x32x16_bf16(qv, k0, a1[0], 0, 0, 0);
      a1[1] = __builtin_amdgcn_mfma_f32_32x32x16_bf16(qv, k1, a1[1], 0, 0, 0);
    }
    __syncthreads();     // B0: all waves done reading Sl of iter kt-1
    // leaky(S/16) -> LDS. C/D 32x32: row=(reg&3)+8*(reg>>2)+4*l5, col=l31
#pragma unroll
    for (int reg = 0; reg < 16; ++reg){
      int rt = mi*32 + (reg & 3) + 8*(reg >> 2) + 4*l5;
      Sl[rt*264 + nj*64 + l31]      = f2bf(lrelu(a1[0][reg]*0.0625f));
      Sl[rt*264 + nj*64 + 32 + l31] = f2bf(lrelu(a1[1][reg]*0.0625f));
    }
    __syncthreads();     // B1: S visible
    // phase 2: acc2 += S[64x256] . V^T[32ch][256keys]
#pragma unroll
    for (int kk = 0; kk < 16; ++kk){
      short8 vf = *(const short8*)(vbase + (size_t)kt*256 + kk*16);
      short8 s0 = *(const short8*)(Sl + (     l31)*264 + kk*16 + l5*8);
      short8 s1 = *(const short8*)(Sl + (32 + l31)*264 + kk*16 + l5*8);
      acc2[0] = __builtin_amdgcn_mfma_f32_32x32x16_bf16(s0, vf, acc2[0], 0, 0, 0);
      acc2[1] = __builtin_amdgcn_mfma_f32_32x32x16_bf16(s1, vf, acc2[1], 0, 0, 0);
    }
  }
#pragma unroll
  for (int mt = 0; mt < 2; ++mt)
#pragma unroll
    for (int reg = 0; reg < 16; ++reg){
      int row = q0 + mt*32 + (reg & 3) + 8*(reg >> 2) + 4*l5;
      P[((size_t)b*4096 + row)*256 + w*32 + l31] = acc2[mt][reg];
    }
}

// ------------------------------------------------- partial reduce + BN stats
__global__ __launch_bounds__(256)
void k_red(const float* __restrict__ P0, const float* __restrict__ P1,
           float* __restrict__ yout, double* __restrict__ st){
  int tid = threadIdx.x;
  int r0 = blockIdx.x*32;
  double sum = 0, sq = 0;
#pragma unroll 4
  for (int r = 0; r < 32; ++r){
    size_t idx = (size_t)(r0 + r)*256 + tid;
    float v = P0[idx] + P1[idx];
    yout[idx] = v;
    sum += v; sq += (double)v*v;
  }
  atomicAdd(&st[1536 + tid], sum);
  atomicAdd(&st[1792 + tid], sq);
}

// --------------------------------------------------------------- softmax
// BN => args are z-scores (|arg|<~6): no max pass needed; shift by a*mu.
__global__ __launch_bounds__(256)
void k_soft1(const float* __restrict__ yout, const double* __restrict__ st,
             const float* __restrict__ g1, float* __restrict__ sums){
  __shared__ float red[256];
  __shared__ float sA[64], sK[64];
  int tid = threadIdx.x;
  int chunk = blockIdx.x, ct = blockIdx.y, b = blockIdx.z;
  int cl = tid & 63, pg = tid >> 6;
  int c = ct*64 + cl;
  if (tid < 64){
    int cc = ct*64 + tid;
    double mu  = st[1536 + cc]*(1.0/NTOT);
    double var = st[1792 + cc]*(1.0/NTOT) - mu*mu;
    double a = g1[cc] / sqrt(var + EPS);
    sA[tid] = (float)a;
    sK[tid] = (float)(a*mu);
  }
  __syncthreads();
  float a = sA[cl], K = sK[cl];
  float s = 0.f;
  const float* base = yout + ((size_t)b*4096 + chunk*256)*256 + c;
#pragma unroll 4
  for (int k = 0; k < 64; ++k){
    float v = base[(size_t)(pg + k*4)*256];
    s += __expf(v*a - K);
  }
  red[tid] = s;
  __syncthreads();
  if (tid < 64){
    float tot = red[tid] + red[64+tid] + red[128+tid] + red[192+tid];
    atomicAdd(&sums[b*256 + ct*64 + tid], tot);
  }
}

__global__ __launch_bounds__(256)
void k_soft2(const float* __restrict__ yout, const double* __restrict__ st,
             const float* __restrict__ g1, const float* __restrict__ sums,
             float* __restrict__ out){
  __shared__ float sA[64], sK[64], sR[64];
  int tid = threadIdx.x;
  int chunk = blockIdx.x, ct = blockIdx.y, b = blockIdx.z;
  int cl = tid & 63, pg = tid >> 6;
  int c = ct*64 + cl;
  if (tid < 64){
    int cc = ct*64 + tid;
    double mu  = st[1536 + cc]*(1.0/NTOT);
    double var = st[1792 + cc]*(1.0/NTOT) - mu*mu;
    double a = g1[cc] / sqrt(var + EPS);
    sA[tid] = (float)a;
    sK[tid] = (float)(a*mu);
    sR[tid] = 1.f / sums[b*256 + cc];
  }
  __syncthreads();
  float a = sA[cl], K = sK[cl], rl = sR[cl];
  const float* base = yout + ((size_t)b*4096 + chunk*256)*256 + c;
  float* obase = out + ((size_t)b*4096 + chunk*256)*256 + c;
#pragma unroll 4
  for (int k = 0; k < 64; ++k){
    size_t idx = (size_t)(pg + k*4)*256;
    obase[idx] = __expf(base[idx]*a - K) * rl;
  }
}

// ---------------------------------------------------------------------------
extern "C" void kernel_launch(void* const* d_in, const int* in_sizes, int n_in,
                              void* d_out, int out_size, void* d_ws, size_t ws_size,
                              hipStream_t stream){
  (void)in_sizes; (void)n_in; (void)out_size; (void)ws_size;
  const float* X  = (const float*)d_in[0];
  const float* Wq = (const float*)d_in[1];
  const float* gq = (const float*)d_in[2];
  const float* bq = (const float*)d_in[3];
  const float* Wk = (const float*)d_in[4];
  const float* gk = (const float*)d_in[5];
  const float* bk = (const float*)d_in[6];
  const float* Wv = (const float*)d_in[7];
  const float* gv = (const float*)d_in[8];
  const float* bv = (const float*)d_in[9];
  const float* g1 = (const float*)d_in[10];
  // d_in[11] = b1: cancels inside the spatial softmax

  char* ws = (char*)d_ws;
  double*         st   = (double*)ws;                        // 2048 f64 (16KB)
  float*          sums = (float*)(ws + 16384);               // 4x256 f32 (4KB)
  unsigned short* Wt   = (unsigned short*)(ws + 20480);      // 768x256 bf16
  unsigned short* Xb   = (unsigned short*)(ws + 413696);     // 16384x256 bf16
  float*          Y    = (float*)(ws + 8802304);             // 16384x768 f32 (48MB)
  unsigned short* Kb   = (unsigned short*)(ws + 59133952);   // 16384x256 bf16
  unsigned short* Vt   = (unsigned short*)(ws + 67522560);   // [4][256][4096] bf16
  // Y region is dead after k_bn_v; reuse it for P0|P1|yout (3x16MB = 48MB)
  unsigned short* Qb   = Xb;                                 // dead after GEMM
  float*          P0   = Y;
  float*          P1   = (float*)((char*)Y + 16777216);
  float*          yo   = (float*)((char*)Y + 33554432);

  hipMemsetAsync(st, 0, 20480, stream);
  k_cvt     <<<4096, 256, 0, stream>>>(X, Xb);
  k_wtrans  <<<768, 256, 0, stream>>>(Wq, Wk, Wv, Wt);
  k_qkv_gemm<<<dim3(256,12), 256, 0, stream>>>(Xb, Wt, Y);
  k_stats1  <<<512, 256, 0, stream>>>(Y, st);
  k_bn_qk   <<<8192, 256, 0, stream>>>(Y, st, gq, bq, gk, bk, Qb, Kb);
  k_bn_v    <<<dim3(64,4,4), 256, 0, stream>>>(Y, st, gv, bv, Vt);
  k_attn    <<<512, 512, 0, stream>>>(Qb, Kb, Vt, P0, P1);
  k_red     <<<512, 256, 0, stream>>>(P0, P1, yo, st);
  k_soft1   <<<dim3(16,4,4), 256, 0, stream>>>(yo, st, g1, sums);
  k_soft2   <<<dim3(16,4,4), 256, 0, stream>>>(yo, st, g1, sums, (float*)d_out);
}

// Round 7
// 252.789 us; speedup vs baseline: 2.4715x; 1.3902x over previous
//
#include <hip/hip_runtime.h>
#include <stdint.h>

// ---------------------------------------------------------------------------
// GroupAttentionLayer: RF=16,STRIDE=16 windows tile the image exactly =>
//   yout = leaky(Q K^T / 16) V  (full dense attention per batch), then BN +
//   spatial softmax (mu/beta cancel; only a_c = g1/sqrt(var+eps) survives).
// B=4, P=4096 px/batch (T=16384 rows), C=256. Inputs fp32, OUTPUT fp32.
// R7: k_attn operands stored FRAGMENT-MAJOR in global so every MFMA fragment
// load is a lane-contiguous 1KB dwordx4 from L2 (R5/R6 used per-lane strided
// loads = 32 scattered 32B segments/inst -> VMEM address-path bound).
//   Qf/Kf[((g*16+ks)*64+lane)*8+j] : row=g*32+(lane&31), ch=ks*16+(lane>>5)*8+j
//   Vf[((gc*256+kp)*64+lane)*8+j]  : ch=(gc&7)*32+(lane&31), key=kp*16+(lane>>5)*8+j
// ---------------------------------------------------------------------------

typedef __attribute__((ext_vector_type(8)))  short short8;   // 8 x bf16
typedef __attribute__((ext_vector_type(4)))  float f32x4;    // 16x16 acc
typedef __attribute__((ext_vector_type(16))) float f32x16;   // 32x32 acc
typedef __attribute__((ext_vector_type(4)))  unsigned short ushort4v;

#define ALPHA 0.3f
#define EPS   1e-3
#define NTOT  16384.0

__device__ __forceinline__ unsigned short f2bf(float f){
  unsigned u = __float_as_uint(f);
  u += 0x7FFFu + ((u>>16)&1u);          // RNE
  return (unsigned short)(u>>16);
}
__device__ __forceinline__ float lrelu(float x){ return x > 0.f ? x : ALPHA*x; }

// --------------------------------------------------------------- X fp32->bf16
__global__ __launch_bounds__(256)
void k_cvt(const float* __restrict__ X, unsigned short* __restrict__ Xb){
  int i = (blockIdx.x*256 + threadIdx.x)*4;
  float4 v = *(const float4*)(X + i);
  ushort4v o; o.x = f2bf(v.x); o.y = f2bf(v.y); o.z = f2bf(v.z); o.w = f2bf(v.w);
  *(ushort4v*)(Xb + i) = o;
}

// --------------------------------------------------------------- W transpose
__global__ __launch_bounds__(256)
void k_wtrans(const float* __restrict__ Wq,
              const float* __restrict__ Wk,
              const float* __restrict__ Wv,
              unsigned short* __restrict__ Wt){
  int o = blockIdx.x*256 + threadIdx.x;          // 0 .. 196608
  int p = o >> 16, rem = o & 65535;
  int j = rem >> 8, c = rem & 255;
  const float* W = (p==0) ? Wq : ((p==1) ? Wk : Wv);
  Wt[o] = f2bf(W[c*256 + j]);
}

// --------------------------------------------------------------- QKV GEMM
// Y[t][n] = sum_c Xb[t][c] * Wt[n][c],  t<16384, n<768. fp32 out.
__global__ __launch_bounds__(256)
void k_qkv_gemm(const unsigned short* __restrict__ X,
                const unsigned short* __restrict__ Wt,
                float* __restrict__ Y){
  __shared__ __align__(16) unsigned short At[64*264];
  __shared__ __align__(16) unsigned short Bt[64*264];
  int tid = threadIdx.x;
  int mb = blockIdx.x, nb = blockIdx.y;
#pragma unroll
  for (int it = 0; it < 8; ++it){
    int s = it*256 + tid;
    int row = s >> 5, ch = s & 31;
    uint4 a = *(const uint4*)(X  + ((size_t)(mb*64 + row))*256 + ch*8);
    uint4 b = *(const uint4*)(Wt + ((size_t)(nb*64 + row))*256 + ch*8);
    *(uint4*)(At + row*264 + ch*8) = a;
    *(uint4*)(Bt + row*264 + ch*8) = b;
  }
  __syncthreads();
  int lane = tid & 63, wv = tid >> 6;
  int ln15 = lane & 15, quad = lane >> 4;
  int rw = (wv & 1)*32, cw = (wv >> 1)*32;     // 2x2 waves, 32x32 each
  f32x4 acc[2][2] = {};
#pragma unroll
  for (int ks = 0; ks < 8; ++ks){
    short8 afr[2], bfr[2];
#pragma unroll
    for (int mt = 0; mt < 2; ++mt){
      int r = rw + mt*16 + ln15;
      afr[mt] = *(const short8*)(At + r*264 + (ks*4+quad)*8);
    }
#pragma unroll
    for (int nt = 0; nt < 2; ++nt){
      int r = cw + nt*16 + ln15;
      bfr[nt] = *(const short8*)(Bt + r*264 + (ks*4+quad)*8);
    }
#pragma unroll
    for (int mt = 0; mt < 2; ++mt)
#pragma unroll
      for (int nt = 0; nt < 2; ++nt)
        acc[mt][nt] = __builtin_amdgcn_mfma_f32_16x16x32_bf16(afr[mt], bfr[nt], acc[mt][nt], 0,0,0);
  }
#pragma unroll
  for (int mt = 0; mt < 2; ++mt)
#pragma unroll
    for (int nt = 0; nt < 2; ++nt)
#pragma unroll
      for (int r = 0; r < 4; ++r){
        int row = mb*64 + rw + mt*16 + quad*4 + r;   // C/D: row = quad*4+reg
        int col = nb*64 + cw + nt*16 + ln15;         //      col = lane&15
        Y[(size_t)row*768 + col] = acc[mt][nt][r];
      }
}

// --------------------------------------------------------------- BN stats (Y)
__global__ __launch_bounds__(256)
void k_stats1(const float* __restrict__ Y, double* __restrict__ st){
  int tid = threadIdx.x;
  int r0 = blockIdx.x * 32;
  float sum[3] = {0,0,0}, sq[3] = {0,0,0};
#pragma unroll 4
  for (int r = 0; r < 32; ++r){
    const float* row = Y + (size_t)(r0 + r)*768;
#pragma unroll
    for (int cg = 0; cg < 3; ++cg){
      float v = row[cg*256 + tid];
      sum[cg] += v; sq[cg] += v*v;
    }
  }
#pragma unroll
  for (int cg = 0; cg < 3; ++cg){
    atomicAdd(&st[cg*256 + tid], (double)sum[cg]);
    atomicAdd(&st[768 + cg*256 + tid], (double)sq[cg]);
  }
}

// --------------------------------------------------------------- BN coefs
// scv/shv[cc]: y_norm = y*scv + shv, cc in [0,768) = Q|K|V channels
__global__ __launch_bounds__(256)
void k_coef(const double* __restrict__ st,
            const float* __restrict__ gq, const float* __restrict__ bq,
            const float* __restrict__ gk, const float* __restrict__ bk,
            const float* __restrict__ gv, const float* __restrict__ bv,
            float* __restrict__ scv, float* __restrict__ shv){
  int cc = blockIdx.x*256 + threadIdx.x;   // 0..767
  int proj = cc >> 8, c = cc & 255;
  double mu  = st[cc]     * (1.0/NTOT);
  double var = st[768+cc] * (1.0/NTOT) - mu*mu;
  double g = (proj==0) ? gq[c] : (proj==1) ? gk[c] : gv[c];
  double b = (proj==0) ? bq[c] : (proj==1) ? bk[c] : bv[c];
  double sc = g / sqrt(var + EPS);
  scv[cc] = (float)sc;
  shv[cc] = (float)(b - mu*sc);
}

// --------------------------------------------------------------- BN+leaky Q,K
// writes fragment-major Qf/Kf. thread: one row t, one 8-ch chunk of Q or K.
__global__ __launch_bounds__(256)
void k_bn_qk(const float* __restrict__ Y,
             const float* __restrict__ scv, const float* __restrict__ shv,
             unsigned short* __restrict__ Qf, unsigned short* __restrict__ Kf){
  int idx = blockIdx.x*256 + threadIdx.x;     // 1M threads
  int t = idx >> 6, cb = idx & 63;
  int proj = cb >> 5, cbl = cb & 31;          // 0=Q, 1=K; 32 chunks of 8 ch
  int ch0 = cbl*8;
  const float* src = Y + (size_t)t*768 + proj*256 + ch0;
  float4 v0 = *(const float4*)(src);
  float4 v1 = *(const float4*)(src + 4);
  const float* sc = scv + proj*256 + ch0;
  const float* sh = shv + proj*256 + ch0;
  unsigned short r[8];
  r[0]=f2bf(lrelu(v0.x*sc[0]+sh[0])); r[1]=f2bf(lrelu(v0.y*sc[1]+sh[1]));
  r[2]=f2bf(lrelu(v0.z*sc[2]+sh[2])); r[3]=f2bf(lrelu(v0.w*sc[3]+sh[3]));
  r[4]=f2bf(lrelu(v1.x*sc[4]+sh[4])); r[5]=f2bf(lrelu(v1.y*sc[5]+sh[5]));
  r[6]=f2bf(lrelu(v1.z*sc[6]+sh[6])); r[7]=f2bf(lrelu(v1.w*sc[7]+sh[7]));
  uint4 u;
  u.x = (unsigned)r[0] | ((unsigned)r[1]<<16);
  u.y = (unsigned)r[2] | ((unsigned)r[3]<<16);
  u.z = (unsigned)r[4] | ((unsigned)r[5]<<16);
  u.w = (unsigned)r[6] | ((unsigned)r[7]<<16);
  int g = t >> 5, l31r = t & 31;
  int ks = cbl >> 1, l5c = cbl & 1;
  unsigned short* dst = (proj ? Kf : Qf) + ((size_t)((g*16 + ks)*64 + l5c*32 + l31r))*8;
  *(uint4*)dst = u;
}

// --------------------------------------------------------------- BN+leaky Vf
// fragment-major V^T via LDS tile transpose
__global__ __launch_bounds__(256)
void k_bn_v(const float* __restrict__ Y,
            const float* __restrict__ scv, const float* __restrict__ shv,
            unsigned short* __restrict__ Vf){
  __shared__ unsigned short tile[64][66];      // [pixelLocal][chLocal]
  int tid = threadIdx.x;
  int pt = blockIdx.x, ct = blockIdx.y, b = blockIdx.z;
  int cl = tid & 63, rq = tid >> 6;
  int c  = ct*64 + cl;
  float sc = scv[512 + c], sh = shv[512 + c];
#pragma unroll 4
  for (int k = 0; k < 16; ++k){
    int r = k*4 + rq;
    size_t t = (size_t)b*4096 + pt*64 + r;
    float v = Y[t*768 + 512 + c];
    tile[r][cl] = f2bf(lrelu(v*sc + sh));
  }
  __syncthreads();
#pragma unroll
  for (int it = 0; it < 2; ++it){
    int m = it*256 + tid;                      // 512 chunks of 8 keys
    int c2 = m >> 3, kg = m & 7;
    int ch = ct*64 + c2;
    int gc = b*8 + (ch >> 5), l31c = ch & 31;
    int kp = pt*4 + (kg >> 1), l5k = kg & 1;
    unsigned short r0 = tile[kg*8+0][c2], r1 = tile[kg*8+1][c2];
    unsigned short r2 = tile[kg*8+2][c2], r3 = tile[kg*8+3][c2];
    unsigned short r4 = tile[kg*8+4][c2], r5 = tile[kg*8+5][c2];
    unsigned short r6 = tile[kg*8+6][c2], r7 = tile[kg*8+7][c2];
    uint4 u;
    u.x = (unsigned)r0 | ((unsigned)r1<<16);
    u.y = (unsigned)r2 | ((unsigned)r3<<16);
    u.z = (unsigned)r4 | ((unsigned)r5<<16);
    u.w = (unsigned)r6 | ((unsigned)r7<<16);
    *(uint4*)(Vf + ((size_t)((gc*256 + kp)*64 + l5k*32 + l31c))*8) = u;
  }
}

// --------------------------------------------------------------- attention
// 512 blocks x 512 threads. blk>>3 = q-tile (64 rows), blk&7 = (b,half) ->
// XCD-pinned (round-robin dispatch) so each XCD's L2 holds its 2MB K/V.
// 8 iters of BK=256 keys, 2 barriers/iter. All global fragment loads are
// lane-contiguous 1KB (fragment-major layouts). Wave w: phase1 owns key
// group w*32 (computes both 32-row halves = 2 chains, no duplicate K reads);
// phase2 owns channels w*32..+32 (2 row-chain accumulators).
__global__ __launch_bounds__(512, 4)
void k_attn(const unsigned short* __restrict__ Qf,
            const unsigned short* __restrict__ Kf,
            const unsigned short* __restrict__ Vf,
            float* __restrict__ P0, float* __restrict__ P1){
  __shared__ __align__(16) unsigned short Ql[64*256];   // frag-major Q tile
  __shared__ __align__(16) unsigned short Sl[64*264];   // [q][key] padded
  int tid = threadIdx.x;
  int blk = blockIdx.x;
  int qt = blk >> 3, combo = blk & 7;
  int b = combo >> 1, half = combo & 1;
  int q0 = qt*64;
  int lane = tid & 63, w = tid >> 6;
  int l31 = lane & 31, l5 = lane >> 5;
  float* P = half ? P1 : P0;

  // stage Q tile: contiguous 32KB copy (fragment-major, identity layout)
  int gq0 = b*128 + qt*2;
  {
    const uint4* src = (const uint4*)(Qf + (size_t)gq0*8192);
    uint4* dst = (uint4*)Ql;
#pragma unroll
    for (int it = 0; it < 4; ++it) dst[it*512 + tid] = src[it*512 + tid];
  }
  __syncthreads();

  f32x16 acc2[2] = {};
  // K frags: wave w owns keys [w*32, w*32+32) of each BK=256 chunk
  int gk0 = b*128 + half*64 + w;               // + kt*8 per iter
  const unsigned short* kb = Kf + (size_t)gk0*8192 + lane*8;
  // V frags: wave w owns channels [w*32, w*32+32)
  const unsigned short* vb = Vf + ((size_t)((b*8 + w)*256 + half*128))*512 + lane*8;
  const unsigned short* qa0 = Ql + lane*8;            // mloc 0, + ks*512
  const unsigned short* qa1 = Ql + 16*512 + lane*8;   // mloc 1

  for (int kt = 0; kt < 8; ++kt){
    // phase 1: S[0..64)[w*32..+32) over K=256, two independent row chains
    f32x16 a1[2] = {};
    const unsigned short* kbt = kb + (size_t)kt*8*8192;
#pragma unroll
    for (int ks = 0; ks < 16; ++ks){
      short8 kf = *(const short8*)(kbt + ks*512);
      short8 q0v = *(const short8*)(qa0 + ks*512);
      short8 q1v = *(const short8*)(qa1 + ks*512);
      a1[0] = __builtin_amdgcn_mfma_f32_32x32x16_bf16(q0v, kf, a1[0], 0, 0, 0);
      a1[1] = __builtin_amdgcn_mfma_f32_32x32x16_bf16(q1v, kf, a1[1], 0, 0, 0);
    }
    __syncthreads();     // B0: all waves done reading Sl of iter kt-1
#pragma unroll
    for (int reg = 0; reg < 16; ++reg){
      int rloc = (reg & 3) + 8*(reg >> 2) + 4*l5;
      Sl[rloc*264 + w*32 + l31]        = f2bf(lrelu(a1[0][reg]*0.0625f));
      Sl[(32 + rloc)*264 + w*32 + l31] = f2bf(lrelu(a1[1][reg]*0.0625f));
    }
    __syncthreads();     // B1: S visible
    // phase 2: acc2 += S[64x256] . V^T[32ch][256keys]
    const unsigned short* vbt = vb + (size_t)kt*16*512;
#pragma unroll
    for (int kk = 0; kk < 16; ++kk){
      short8 vf = *(const short8*)(vbt + kk*512);
      short8 s0 = *(const short8*)(Sl + (     l31)*264 + kk*16 + l5*8);
      short8 s1 = *(const short8*)(Sl + (32 + l31)*264 + kk*16 + l5*8);
      acc2[0] = __builtin_amdgcn_mfma_f32_32x32x16_bf16(s0, vf, acc2[0], 0, 0, 0);
      acc2[1] = __builtin_amdgcn_mfma_f32_32x32x16_bf16(s1, vf, acc2[1], 0, 0, 0);
    }
  }
#pragma unroll
  for (int c = 0; c < 2; ++c)
#pragma unroll
    for (int reg = 0; reg < 16; ++reg){
      int row = q0 + c*32 + (reg & 3) + 8*(reg >> 2) + 4*l5;
      P[((size_t)b*4096 + row)*256 + w*32 + l31] = acc2[c][reg];
    }
}

// ------------------------------------------------- partial reduce + BN stats
__global__ __launch_bounds__(256)
void k_red(const float* __restrict__ P0, const float* __restrict__ P1,
           float* __restrict__ yout, double* __restrict__ st){
  int tid = threadIdx.x;
  int r0 = blockIdx.x*32;
  double sum = 0, sq = 0;
#pragma unroll 4
  for (int r = 0; r < 32; ++r){
    size_t idx = (size_t)(r0 + r)*256 + tid;
    float v = P0[idx] + P1[idx];
    yout[idx] = v;
    sum += v; sq += (double)v*v;
  }
  atomicAdd(&st[1536 + tid], sum);
  atomicAdd(&st[1792 + tid], sq);
}

// --------------------------------------------------------------- softmax
// BN => args are z-scores: no max pass needed; shift by a*mu.
__global__ __launch_bounds__(256)
void k_soft1(const float* __restrict__ yout, const double* __restrict__ st,
             const float* __restrict__ g1, float* __restrict__ sums){
  __shared__ float red[256];
  __shared__ float sA[64], sK[64];
  int tid = threadIdx.x;
  int chunk = blockIdx.x, ct = blockIdx.y, b = blockIdx.z;
  int cl = tid & 63, pg = tid >> 6;
  int c = ct*64 + cl;
  if (tid < 64){
    int cc = ct*64 + tid;
    double mu  = st[1536 + cc]*(1.0/NTOT);
    double var = st[1792 + cc]*(1.0/NTOT) - mu*mu;
    double a = g1[cc] / sqrt(var + EPS);
    sA[tid] = (float)a;
    sK[tid] = (float)(a*mu);
  }
  __syncthreads();
  float a = sA[cl], K = sK[cl];
  float s = 0.f;
  const float* base = yout + ((size_t)b*4096 + chunk*256)*256 + c;
#pragma unroll 4
  for (int k = 0; k < 64; ++k){
    float v = base[(size_t)(pg + k*4)*256];
    s += __expf(v*a - K);
  }
  red[tid] = s;
  __syncthreads();
  if (tid < 64){
    float tot = red[tid] + red[64+tid] + red[128+tid] + red[192+tid];
    atomicAdd(&sums[b*256 + ct*64 + tid], tot);
  }
}

__global__ __launch_bounds__(256)
void k_soft2(const float* __restrict__ yout, const double* __restrict__ st,
             const float* __restrict__ g1, const float* __restrict__ sums,
             float* __restrict__ out){
  __shared__ float sA[64], sK[64], sR[64];
  int tid = threadIdx.x;
  int chunk = blockIdx.x, ct = blockIdx.y, b = blockIdx.z;
  int cl = tid & 63, pg = tid >> 6;
  int c = ct*64 + cl;
  if (tid < 64){
    int cc = ct*64 + tid;
    double mu  = st[1536 + cc]*(1.0/NTOT);
    double var = st[1792 + cc]*(1.0/NTOT) - mu*mu;
    double a = g1[cc] / sqrt(var + EPS);
    sA[tid] = (float)a;
    sK[tid] = (float)(a*mu);
    sR[tid] = 1.f / sums[b*256 + cc];
  }
  __syncthreads();
  float a = sA[cl], K = sK[cl], rl = sR[cl];
  const float* base = yout + ((size_t)b*4096 + chunk*256)*256 + c;
  float* obase = out + ((size_t)b*4096 + chunk*256)*256 + c;
#pragma unroll 4
  for (int k = 0; k < 64; ++k){
    size_t idx = (size_t)(pg + k*4)*256;
    obase[idx] = __expf(base[idx]*a - K) * rl;
  }
}

// ---------------------------------------------------------------------------
extern "C" void kernel_launch(void* const* d_in, const int* in_sizes, int n_in,
                              void* d_out, int out_size, void* d_ws, size_t ws_size,
                              hipStream_t stream){
  (void)in_sizes; (void)n_in; (void)out_size; (void)ws_size;
  const float* X  = (const float*)d_in[0];
  const float* Wq = (const float*)d_in[1];
  const float* gq = (const float*)d_in[2];
  const float* bq = (const float*)d_in[3];
  const float* Wk = (const float*)d_in[4];
  const float* gk = (const float*)d_in[5];
  const float* bk = (const float*)d_in[6];
  const float* Wv = (const float*)d_in[7];
  const float* gv = (const float*)d_in[8];
  const float* bv = (const float*)d_in[9];
  const float* g1 = (const float*)d_in[10];
  // d_in[11] = b1: cancels inside the spatial softmax

  char* ws = (char*)d_ws;
  double*         st   = (double*)ws;                        // 2048 f64 (16KB)
  float*          sums = (float*)(ws + 16384);               // 4KB
  float*          scv  = (float*)(ws + 20480);               // 768 f32
  float*          shv  = (float*)(ws + 23552);               // 768 f32
  unsigned short* Wt   = (unsigned short*)(ws + 26624);      // 768x256 bf16
  unsigned short* Xb   = (unsigned short*)(ws + 419840);     // 16384x256 bf16
  float*          Y    = (float*)(ws + 8808448);             // 16384x768 f32
  unsigned short* Kf   = (unsigned short*)(ws + 59140096);   // frag-major 8MB
  unsigned short* Vf   = (unsigned short*)(ws + 67528704);   // frag-major 8MB
  // overlays: Qf on Xb (dead after GEMM); P0|P1|yout on Y (dead after bn_v)
  unsigned short* Qf   = Xb;
  float*          P0   = Y;
  float*          P1   = (float*)((char*)Y + 16777216);
  float*          yo   = (float*)((char*)Y + 33554432);

  hipMemsetAsync(st, 0, 20480, stream);
  k_cvt     <<<4096, 256, 0, stream>>>(X, Xb);
  k_wtrans  <<<768, 256, 0, stream>>>(Wq, Wk, Wv, Wt);
  k_qkv_gemm<<<dim3(256,12), 256, 0, stream>>>(Xb, Wt, Y);
  k_stats1  <<<512, 256, 0, stream>>>(Y, st);
  k_coef    <<<3, 256, 0, stream>>>(st, gq, bq, gk, bk, gv, bv, scv, shv);
  k_bn_qk   <<<4096, 256, 0, stream>>>(Y, scv, shv, Qf, Kf);
  k_bn_v    <<<dim3(64,4,4), 256, 0, stream>>>(Y, scv, shv, Vf);
  k_attn    <<<512, 512, 0, stream>>>(Qf, Kf, Vf, P0, P1);
  k_red     <<<512, 256, 0, stream>>>(P0, P1, yo, st);
  k_soft1   <<<dim3(16,4,4), 256, 0, stream>>>(yo, st, g1, sums);
  k_soft2   <<<dim3(16,4,4), 256, 0, stream>>>(yo, st, g1, sums, (float*)d_out);
}